// Round 7
// baseline (579.685 us; speedup 1.0000x reference)
//
#include <hip/hip_runtime.h>

// ---------------------------------------------------------------------------
// QTranBase: twin 3-layer MLPs via bf16 MFMA.
// R7: NO-LDS register-fragment GEMM. R6 showed LDS floor == MFMA floor ==
// 25us but observed 73us: the stage->drain->barrier->ds_read->MFMA lockstep
// is the wall (m97 plateau). Both A[m][k] and B[n][k] give 16-contiguous-
// byte fragments -> global_load_dwordx4 direct to regs, zero barriers,
// compiler interleaves vmcnt with MFMA (AITER-style). fp32->bf16 conversion
// folds into layer1's A-frag load (X buffer + convert pass eliminated).
// ---------------------------------------------------------------------------

#define ROWS 32768
#define EMBED 512

using frag_ab = __attribute__((ext_vector_type(8))) short;   // 8 x bf16
using f32x4   = __attribute__((ext_vector_type(4))) float;   // MFMA C/D

__device__ __forceinline__ unsigned short f2bf(float f) {
    unsigned int u = __builtin_bit_cast(unsigned int, f);
    return (unsigned short)((u + 0x7fffu + ((u >> 16) & 1u)) >> 16);
}

__device__ __forceinline__ unsigned pk2rne(float lo, float hi) {
    return (unsigned)f2bf(lo) | ((unsigned)f2bf(hi) << 16);
}

__device__ __forceinline__ frag_ab pack8(float4 a, float4 b) {
    union { frag_ab f; unsigned u[4]; } r;
    r.u[0] = pk2rne(a.x, a.y); r.u[1] = pk2rne(a.z, a.w);
    r.u[2] = pk2rne(b.x, b.y); r.u[3] = pk2rne(b.z, b.w);
    return r.f;
}

// 2048 blocks -> (m-tile 0..255, nq 0..7); same-m (8 blocks) -> same XCD.
__device__ __forceinline__ void decode_mn(int L, int& mi, int& nq) {
    nq = (L >> 3) & 7;
    mi = ((L >> 6) << 3) | (L & 7);
}

// ---------------------------------------------------------------------------
// prep: blocks [0,320) LDS-tiled coalesced weight transpose fp32->bf16;
// blocks [320,576) seed out with layer-3 bias.
// ---------------------------------------------------------------------------
__global__ __launch_bounds__(256)
void prep(const float* __restrict__ Qw1, const float* __restrict__ Qw2,
          const float* __restrict__ Vw1, const float* __restrict__ Vw2,
          const float* __restrict__ qb3, const float* __restrict__ vb3,
          unsigned short* __restrict__ Qw1t, unsigned short* __restrict__ Qw2t,
          unsigned short* __restrict__ Vw1t, unsigned short* __restrict__ Vw2t,
          float* __restrict__ out) {
    const int b = blockIdx.x, tid = threadIdx.x;
    if (b < 320) {
        __shared__ unsigned short T[64 * 65];
        const float* W; unsigned short* O; int ldo, kt, nt;
        if (b < 128) { W = Qw1; O = Qw1t; ldo = 1024; kt = b >> 3; nt = b & 7; }
        else {
            int c = b - 128, which = c >> 6, r = c & 63;
            kt = r >> 3; nt = r & 7; ldo = 512;
            W = (which == 0) ? Qw2 : (which == 1) ? Vw1 : Vw2;
            O = (which == 0) ? Qw2t : (which == 1) ? Vw1t : Vw2t;
        }
        const int k0 = kt * 64, n0 = nt * 64;
#pragma unroll
        for (int p = 0; p < 16; p++) {          // coalesced read W[k][n]
            int e = tid + p * 256, kr = e >> 6, nc = e & 63;
            T[nc * 65 + kr] = f2bf(W[(size_t)(k0 + kr) * 512 + n0 + nc]);
        }
        __syncthreads();
#pragma unroll
        for (int p = 0; p < 16; p++) {          // coalesced write Wt[n][k]
            int e = tid + p * 256, nr = e >> 6, kc = e & 63;
            O[(size_t)(n0 + nr) * ldo + k0 + kc] = T[nr * 65 + kc];
        }
    } else {
        int i = (b - 320) * 256 + tid;          // out seed: [0,ROWS)=Qb3, rest Vb3
        out[i] = (i < ROWS) ? qb3[0] : vb3[0];
    }
}

// ---------------------------------------------------------------------------
// Layer 1 (Q+V): h1 = relu([states|actions] @ Wt^T + bias), fp32 A packed
// inline. 128x128 block, 2x2 waves of 64x64, register fragments, no LDS.
// nq<4 -> Q (K=1024: states then actions), >=4 -> V (K=512: states).
// ---------------------------------------------------------------------------
__global__ __launch_bounds__(256, 3)
void layer1(const float* __restrict__ states, const float* __restrict__ actions,
            const unsigned short* __restrict__ Qw1t,
            const unsigned short* __restrict__ Vw1t,
            const float* __restrict__ Qb1, const float* __restrict__ Vb1,
            unsigned short* __restrict__ h1Q, unsigned short* __restrict__ h1V) {
    const int tid = threadIdx.x, wave = tid >> 6, lane = tid & 63;
    int mi, nq; decode_mn(blockIdx.x, mi, nq);
    const bool isV = nq >= 4;
    const int bn = (nq & 3) * 128, bm = mi * 128;
    const int ldb = isV ? 512 : 1024;
    const unsigned short* Wt = isV ? Vw1t : Qw1t;
    const float* bias = isV ? Vb1 : Qb1;
    unsigned short* H = isV ? h1V : h1Q;

    const int wm = (wave & 1) * 64, wn = (wave >> 1) * 64;
    const int lrow = lane & 15, quad = lane >> 4;
    f32x4 acc[4][4] = {};

    const float* aRow[4];
    const unsigned short* bRow[4];
#pragma unroll
    for (int i = 0; i < 4; i++)
        aRow[i] = states + (size_t)(bm + wm + i * 16 + lrow) * 512 + quad * 8;
#pragma unroll
    for (int j = 0; j < 4; j++)
        bRow[j] = Wt + (size_t)(bn + wn + j * 16 + lrow) * ldb + quad * 8;

    // phase 1: k = 0..511 over states
#pragma unroll 2
    for (int k = 0; k < 512; k += 32) {
        frag_ab af[4], bf[4];
#pragma unroll
        for (int i = 0; i < 4; i++) {
            float4 x = *(const float4*)(aRow[i] + k);
            float4 y = *(const float4*)(aRow[i] + k + 4);
            af[i] = pack8(x, y);
        }
#pragma unroll
        for (int j = 0; j < 4; j++) bf[j] = *(const frag_ab*)(bRow[j] + k);
#pragma unroll
        for (int i = 0; i < 4; i++)
#pragma unroll
            for (int j = 0; j < 4; j++)
                acc[i][j] = __builtin_amdgcn_mfma_f32_16x16x32_bf16(
                    af[i], bf[j], acc[i][j], 0, 0, 0);
    }

    if (!isV) {
        // phase 2: k = 512..1023 over actions (B offset +512)
        const float* a2[4];
#pragma unroll
        for (int i = 0; i < 4; i++)
            a2[i] = actions + (size_t)(bm + wm + i * 16 + lrow) * 512 + quad * 8;
#pragma unroll 2
        for (int k = 0; k < 512; k += 32) {
            frag_ab af[4], bf[4];
#pragma unroll
            for (int i = 0; i < 4; i++) {
                float4 x = *(const float4*)(a2[i] + k);
                float4 y = *(const float4*)(a2[i] + k + 4);
                af[i] = pack8(x, y);
            }
#pragma unroll
            for (int j = 0; j < 4; j++) bf[j] = *(const frag_ab*)(bRow[j] + 512 + k);
#pragma unroll
            for (int i = 0; i < 4; i++)
#pragma unroll
                for (int j = 0; j < 4; j++)
                    acc[i][j] = __builtin_amdgcn_mfma_f32_16x16x32_bf16(
                        af[i], bf[j], acc[i][j], 0, 0, 0);
        }
    }

    // h1[row][col] = bf16(relu(acc + bias[col]))
#pragma unroll
    for (int j = 0; j < 4; j++) {
        const int col = bn + wn + j * 16 + lrow;
        const float bc = bias[col];
#pragma unroll
        for (int i = 0; i < 4; i++) {
            const int row0 = bm + wm + i * 16 + quad * 4;
#pragma unroll
            for (int r = 0; r < 4; r++) {
                float v = acc[i][j][r] + bc;
                v = v > 0.0f ? v : 0.0f;
                H[(size_t)(row0 + r) * EMBED + col] = f2bf(v);
            }
        }
    }
}

// ---------------------------------------------------------------------------
// Layer 2+3 (Q+V): out[row] += sum_n relu(h1 @ W2^T + b2)[n] * w3[n].
// Register fragments, no LDS, K=512, fused layer-3 epilogue.
// ---------------------------------------------------------------------------
__global__ __launch_bounds__(256, 3)
void layer2(const unsigned short* __restrict__ h1Q,
            const unsigned short* __restrict__ h1V,
            const unsigned short* __restrict__ Qw2t,
            const unsigned short* __restrict__ Vw2t,
            const float* __restrict__ Qb2, const float* __restrict__ Vb2,
            const float* __restrict__ Qw3, const float* __restrict__ Vw3,
            float* __restrict__ out) {
    const int tid = threadIdx.x, wave = tid >> 6, lane = tid & 63;
    int mi, nq; decode_mn(blockIdx.x, mi, nq);
    const bool isV = nq >= 4;
    const int bn = (nq & 3) * 128, bm = mi * 128;
    const unsigned short* A  = isV ? h1V : h1Q;
    const unsigned short* Wt = isV ? Vw2t : Qw2t;
    const float* bias = isV ? Vb2 : Qb2;
    const float* w3   = isV ? Vw3 : Qw3;
    float* op = out + (isV ? ROWS : 0);

    const int wm = (wave & 1) * 64, wn = (wave >> 1) * 64;
    const int lrow = lane & 15, quad = lane >> 4;
    f32x4 acc[4][4] = {};

    const unsigned short* aRow[4];
    const unsigned short* bRow[4];
#pragma unroll
    for (int i = 0; i < 4; i++)
        aRow[i] = A + (size_t)(bm + wm + i * 16 + lrow) * 512 + quad * 8;
#pragma unroll
    for (int j = 0; j < 4; j++)
        bRow[j] = Wt + (size_t)(bn + wn + j * 16 + lrow) * 512 + quad * 8;

#pragma unroll 2
    for (int k = 0; k < 512; k += 32) {
        frag_ab af[4], bf[4];
#pragma unroll
        for (int i = 0; i < 4; i++) af[i] = *(const frag_ab*)(aRow[i] + k);
#pragma unroll
        for (int j = 0; j < 4; j++) bf[j] = *(const frag_ab*)(bRow[j] + k);
#pragma unroll
        for (int i = 0; i < 4; i++)
#pragma unroll
            for (int j = 0; j < 4; j++)
                acc[i][j] = __builtin_amdgcn_mfma_f32_16x16x32_bf16(
                    af[i], bf[j], acc[i][j], 0, 0, 0);
    }

    // fused layer 3
    float bc[4], wc[4];
#pragma unroll
    for (int j = 0; j < 4; j++) {
        const int col = bn + wn + j * 16 + lrow;
        bc[j] = bias[col];
        wc[j] = w3[col];
    }
#pragma unroll
    for (int i = 0; i < 4; i++) {
#pragma unroll
        for (int r = 0; r < 4; r++) {
            float s = 0.0f;
#pragma unroll
            for (int j = 0; j < 4; j++) {
                float v = acc[i][j][r] + bc[j];
                v = v > 0.0f ? v : 0.0f;
                s += v * wc[j];
            }
#pragma unroll
            for (int m = 1; m < 16; m <<= 1) s += __shfl_xor(s, m, 64);
            if (lrow == 0)
                atomicAdd(&op[bm + wm + i * 16 + quad * 4 + r], s);
        }
    }
}

extern "C" void kernel_launch(void* const* d_in, const int* in_sizes, int n_in,
                              void* d_out, int out_size, void* d_ws, size_t ws_size,
                              hipStream_t stream) {
    const float* states  = (const float*)d_in[0];
    const float* actions = (const float*)d_in[1];
    const float* Qw1 = (const float*)d_in[2];
    const float* Qb1 = (const float*)d_in[3];
    const float* Qw2 = (const float*)d_in[4];
    const float* Qb2 = (const float*)d_in[5];
    const float* Qw3 = (const float*)d_in[6];
    const float* Qb3 = (const float*)d_in[7];
    const float* Vw1 = (const float*)d_in[8];
    const float* Vb1 = (const float*)d_in[9];
    const float* Vw2 = (const float*)d_in[10];
    const float* Vb2 = (const float*)d_in[11];
    const float* Vw3 = (const float*)d_in[12];
    const float* Vb3 = (const float*)d_in[13];
    float* out = (float*)d_out;

    // workspace layout (bytes)
    char* ws = (char*)d_ws;
    unsigned short* h1Q  = (unsigned short*)ws;                        // 32 MB
    unsigned short* h1V  = (unsigned short*)(ws + 33554432);           // 32 MB
    unsigned short* Qw1t = (unsigned short*)(ws + 67108864);           // 1 MB
    unsigned short* Qw2t = Qw1t + 512 * 1024;
    unsigned short* Vw1t = Qw2t + 512 * 512;
    unsigned short* Vw2t = Vw1t + 512 * 512;

    prep<<<dim3(576), dim3(256), 0, stream>>>(Qw1, Qw2, Vw1, Vw2, Qb3, Vb3,
                                              Qw1t, Qw2t, Vw1t, Vw2t, out);

    layer1<<<dim3(2048), dim3(256), 0, stream>>>(states, actions, Qw1t, Vw1t,
                                                 Qb1, Vb1, h1Q, h1V);
    layer2<<<dim3(2048), dim3(256), 0, stream>>>(h1Q, h1V, Qw2t, Vw2t,
                                                 Qb2, Vb2, Qw3, Vw3, out);
}

// Round 8
// 305.672 us; speedup vs baseline: 1.8964x; 1.8964x over previous
//
#include <hip/hip_runtime.h>

// ---------------------------------------------------------------------------
// QTranBase: twin 3-layer MLPs via bf16 MFMA.
// R8: R6 tile (128x256, wave 64x128) + PIPELINED double-buffered staging:
// BK=32, stage(k+1) issued after the barrier and before compute(k), so the
// global->LDS DMA overlaps the ds_read+MFMA phase (AITER-style overlap the
// 2-barrier loop can't express; R6's stage->drain->compute serialized).
// 48 KB LDS total (2 x 24 KB) = 2 blocks/CU, same as R6.
// R7 lesson kept: frag loads MUST be coalesced-staged (direct reg-frag
// loads are 16x transaction-amplified -> 5.8% MfmaUtil).
// ---------------------------------------------------------------------------

#define ROWS 32768
#define EMBED 512

using frag_ab = __attribute__((ext_vector_type(8))) short;   // 8 x bf16
using f32x4   = __attribute__((ext_vector_type(4))) float;   // MFMA C/D

__device__ __forceinline__ unsigned short f2bf(float f) {
    unsigned int u = __builtin_bit_cast(unsigned int, f);
    return (unsigned short)((u + 0x7fffu + ((u >> 16) & 1u)) >> 16);
}

__device__ __forceinline__ unsigned pk2rne(float lo, float hi) {
    return (unsigned)f2bf(lo) | ((unsigned)f2bf(hi) << 16);
}

__device__ __forceinline__ void async_copy16(const void* g, void* l) {
    // dest = wave-uniform LDS base; HW writes base + lane*16
    __builtin_amdgcn_global_load_lds(
        (const __attribute__((address_space(1))) unsigned int*)g,
        (__attribute__((address_space(3))) unsigned int*)l, 16, 0, 0);
}

// 1024 blocks -> (m-tile 0..255, nq 0..3); same-m (4 blocks) -> same XCD.
// nq: 0,1 = Q n-halves; 2,3 = V n-halves.
__device__ __forceinline__ void decode_mn(int L, int& mi, int& nq) {
    nq = (L >> 3) & 3;
    mi = ((L >> 5) << 3) | (L & 7);
}

// ---------------------------------------------------------------------------
// prep: [0,4096) convert X (32 elems/thread); [4096,4416) LDS-tiled coalesced
// weight transpose; [4416,4672) seed out with layer-3 bias.
// ---------------------------------------------------------------------------
__global__ __launch_bounds__(256)
void prep(const float* __restrict__ states, const float* __restrict__ actions,
          const float* __restrict__ Qw1, const float* __restrict__ Qw2,
          const float* __restrict__ Vw1, const float* __restrict__ Vw2,
          const float* __restrict__ qb3, const float* __restrict__ vb3,
          unsigned short* __restrict__ X,
          unsigned short* __restrict__ Qw1t, unsigned short* __restrict__ Qw2t,
          unsigned short* __restrict__ Vw1t, unsigned short* __restrict__ Vw2t,
          float* __restrict__ out) {
    const int b = blockIdx.x, tid = threadIdx.x;
    if (b < 4096) {
        int c = b * 256 + tid;            // chunk of 32 within one row
        int m = c >> 5, col = (c & 31) * 32;
        const float* src = (col < 512) ? states + (size_t)m * 512 + col
                                       : actions + (size_t)m * 512 + (col - 512);
        float4 f[8];
#pragma unroll
        for (int i = 0; i < 8; i++) f[i] = ((const float4*)src)[i];
        uint4* dst = (uint4*)(X + (size_t)m * 1024 + col);
#pragma unroll
        for (int i = 0; i < 4; i++)
            dst[i] = make_uint4(pk2rne(f[2*i].x,   f[2*i].y),
                                pk2rne(f[2*i].z,   f[2*i].w),
                                pk2rne(f[2*i+1].x, f[2*i+1].y),
                                pk2rne(f[2*i+1].z, f[2*i+1].w));
    } else if (b < 4416) {
        // 64x64 LDS-tiled transpose, coalesced on both sides
        __shared__ unsigned short T[64 * 65];
        const int c = b - 4096;
        const float* W; unsigned short* O; int ldo, kt, nt;
        if (c < 128) { W = Qw1; O = Qw1t; ldo = 1024; kt = c >> 3; nt = c & 7; }
        else {
            int d = c - 128, which = d >> 6, r = d & 63;
            kt = r >> 3; nt = r & 7; ldo = 512;
            W = (which == 0) ? Qw2 : (which == 1) ? Vw1 : Vw2;
            O = (which == 0) ? Qw2t : (which == 1) ? Vw1t : Vw2t;
        }
        const int k0 = kt * 64, n0 = nt * 64;
#pragma unroll
        for (int p = 0; p < 16; p++) {          // coalesced read W[k][n]
            int e = tid + p * 256, kr = e >> 6, nc = e & 63;
            T[nc * 65 + kr] = f2bf(W[(size_t)(k0 + kr) * 512 + n0 + nc]);
        }
        __syncthreads();
#pragma unroll
        for (int p = 0; p < 16; p++) {          // coalesced write Wt[n][k]
            int e = tid + p * 256, nr = e >> 6, kc = e & 63;
            O[(size_t)(n0 + nr) * ldo + k0 + kc] = T[nr * 65 + kc];
        }
    } else {
        int i = (b - 4416) * 256 + tid;
        out[i] = (i < ROWS) ? qb3[0] : vb3[0];
    }
}

// ---------------------------------------------------------------------------
// Layer 1 (Q+V): h1 = relu(X @ Wt^T + bias). nq<2 -> Q (K=1024),
// >=2 -> V (K=512). Block 128x256, waves 2x2 of 64x128, BK=32,
// double-buffered pipelined staging.
// ---------------------------------------------------------------------------
__global__ __launch_bounds__(256, 2)
void layer1(const unsigned short* __restrict__ X,
            const unsigned short* __restrict__ Qw1t,
            const unsigned short* __restrict__ Vw1t,
            const float* __restrict__ Qb1, const float* __restrict__ Vb1,
            unsigned short* __restrict__ h1Q, unsigned short* __restrict__ h1V) {
    __shared__ __align__(16) unsigned short As[2 * 4096];   // 2 bufs x 128r x 32
    __shared__ __align__(16) unsigned short Bs[2 * 8192];   // 2 bufs x 256r x 32

    const int tid = threadIdx.x, wave = tid >> 6, lane = tid & 63;
    int mi, nq; decode_mn(blockIdx.x, mi, nq);
    const bool isV = nq >= 2;
    const int bn = (nq & 1) * 256;
    const int bm = mi * 128;
    const int K = isV ? 512 : 1024;           // ldb == K for both weights
    const unsigned short* Wt = isV ? Vw1t : Qw1t;
    const float* bias = isV ? Vb1 : Qb1;
    unsigned short* H = isV ? h1V : h1Q;

    const int wm = (wave & 1) * 64, wn = (wave >> 1) * 128;
    const int lrow = lane & 15, quad = lane >> 4;
    f32x4 acc[4][8] = {};

    const int lin  = wave * 1024 + lane * 16;
    const int rowS = lin >> 6, colS = (lin & 63) >> 1;
    const unsigned short* gA0 = X + (size_t)(bm + rowS)      * 1024 + colS;
    const unsigned short* gA1 = X + (size_t)(bm + rowS + 64) * 1024 + colS;
    const unsigned short* gB0 = Wt + (size_t)(bn + rowS)       * K + colS;
    const unsigned short* gB1 = Wt + (size_t)(bn + rowS + 64)  * K + colS;
    const unsigned short* gB2 = Wt + (size_t)(bn + rowS + 128) * K + colS;
    const unsigned short* gB3 = Wt + (size_t)(bn + rowS + 192) * K + colS;
    unsigned short* ldsA0 = As + wave * 512;
    unsigned short* ldsA1 = As + 2048 + wave * 512;
    unsigned short* ldsB0 = Bs + wave * 512;
    unsigned short* ldsB1 = Bs + 2048 + wave * 512;
    unsigned short* ldsB2 = Bs + 4096 + wave * 512;
    unsigned short* ldsB3 = Bs + 6144 + wave * 512;

    const int nIter = K >> 5;
    // prologue: stage iter 0 into buffer 0
    async_copy16(gA0, ldsA0);  async_copy16(gA1, ldsA1);
    async_copy16(gB0, ldsB0);  async_copy16(gB1, ldsB1);
    async_copy16(gB2, ldsB2);  async_copy16(gB3, ldsB3);
    gA0 += 32; gA1 += 32; gB0 += 32; gB1 += 32; gB2 += 32; gB3 += 32;

    for (int it = 0; it < nIter; ++it) {
        __syncthreads();                       // buf[it&1] ready (drains DMA)
        if (it + 1 < nIter) {                  // stage it+1 -> other buffer,
            const int p = ((it + 1) & 1);      // overlaps compute below
            async_copy16(gA0, ldsA0 + p * 4096);
            async_copy16(gA1, ldsA1 + p * 4096);
            async_copy16(gB0, ldsB0 + p * 8192);
            async_copy16(gB1, ldsB1 + p * 8192);
            async_copy16(gB2, ldsB2 + p * 8192);
            async_copy16(gB3, ldsB3 + p * 8192);
            gA0 += 32; gA1 += 32; gB0 += 32; gB1 += 32; gB2 += 32; gB3 += 32;
        }
        const unsigned short* Ab = As + (it & 1) * 4096;
        const unsigned short* Bb = Bs + (it & 1) * 8192;
        frag_ab af[4], bfr[8];
#pragma unroll
        for (int i = 0; i < 4; i++)
            af[i] = *(const frag_ab*)&Ab[(wm + i * 16 + lrow) * 32 + quad * 8];
#pragma unroll
        for (int j = 0; j < 8; j++)
            bfr[j] = *(const frag_ab*)&Bb[(wn + j * 16 + lrow) * 32 + quad * 8];
#pragma unroll
        for (int i = 0; i < 4; i++)
#pragma unroll
            for (int j = 0; j < 8; j++)
                acc[i][j] = __builtin_amdgcn_mfma_f32_16x16x32_bf16(
                    af[i], bfr[j], acc[i][j], 0, 0, 0);
    }

    // h1[row][col] = bf16(relu(acc + bias[col]))
#pragma unroll
    for (int j = 0; j < 8; j++) {
        const int col = bn + wn + j * 16 + lrow;
        const float bc = bias[col];
#pragma unroll
        for (int i = 0; i < 4; i++) {
            const int row0 = bm + wm + i * 16 + quad * 4;
#pragma unroll
            for (int r = 0; r < 4; r++) {
                float v = acc[i][j][r] + bc;
                v = v > 0.0f ? v : 0.0f;
                H[(size_t)(row0 + r) * EMBED + col] = f2bf(v);
            }
        }
    }
}

// ---------------------------------------------------------------------------
// Layer 2+3 (Q+V): out[row] += sum_n relu(h1 @ W2^T + b2)[n] * w3[n].
// Same pipelined structure, K=512, fused layer-3 epilogue.
// ---------------------------------------------------------------------------
__global__ __launch_bounds__(256, 2)
void layer2(const unsigned short* __restrict__ h1Q,
            const unsigned short* __restrict__ h1V,
            const unsigned short* __restrict__ Qw2t,
            const unsigned short* __restrict__ Vw2t,
            const float* __restrict__ Qb2, const float* __restrict__ Vb2,
            const float* __restrict__ Qw3, const float* __restrict__ Vw3,
            float* __restrict__ out) {
    __shared__ __align__(16) unsigned short As[2 * 4096];
    __shared__ __align__(16) unsigned short Bs[2 * 8192];

    const int tid = threadIdx.x, wave = tid >> 6, lane = tid & 63;
    int mi, nq; decode_mn(blockIdx.x, mi, nq);
    const bool isV = nq >= 2;
    const int bn = (nq & 1) * 256;
    const int bm = mi * 128;
    const unsigned short* A  = isV ? h1V : h1Q;
    const unsigned short* Wt = isV ? Vw2t : Qw2t;
    const float* bias = isV ? Vb2 : Qb2;
    const float* w3   = isV ? Vw3 : Qw3;
    float* op = out + (isV ? ROWS : 0);

    const int wm = (wave & 1) * 64, wn = (wave >> 1) * 128;
    const int lrow = lane & 15, quad = lane >> 4;
    f32x4 acc[4][8] = {};

    const int lin  = wave * 1024 + lane * 16;
    const int rowS = lin >> 6, colS = (lin & 63) >> 1;
    const unsigned short* gA0 = A + (size_t)(bm + rowS)      * 512 + colS;
    const unsigned short* gA1 = A + (size_t)(bm + rowS + 64) * 512 + colS;
    const unsigned short* gB0 = Wt + (size_t)(bn + rowS)       * 512 + colS;
    const unsigned short* gB1 = Wt + (size_t)(bn + rowS + 64)  * 512 + colS;
    const unsigned short* gB2 = Wt + (size_t)(bn + rowS + 128) * 512 + colS;
    const unsigned short* gB3 = Wt + (size_t)(bn + rowS + 192) * 512 + colS;
    unsigned short* ldsA0 = As + wave * 512;
    unsigned short* ldsA1 = As + 2048 + wave * 512;
    unsigned short* ldsB0 = Bs + wave * 512;
    unsigned short* ldsB1 = Bs + 2048 + wave * 512;
    unsigned short* ldsB2 = Bs + 4096 + wave * 512;
    unsigned short* ldsB3 = Bs + 6144 + wave * 512;

    async_copy16(gA0, ldsA0);  async_copy16(gA1, ldsA1);
    async_copy16(gB0, ldsB0);  async_copy16(gB1, ldsB1);
    async_copy16(gB2, ldsB2);  async_copy16(gB3, ldsB3);
    gA0 += 32; gA1 += 32; gB0 += 32; gB1 += 32; gB2 += 32; gB3 += 32;

    for (int it = 0; it < 16; ++it) {          // K=512, BK=32
        __syncthreads();
        if (it + 1 < 16) {
            const int p = ((it + 1) & 1);
            async_copy16(gA0, ldsA0 + p * 4096);
            async_copy16(gA1, ldsA1 + p * 4096);
            async_copy16(gB0, ldsB0 + p * 8192);
            async_copy16(gB1, ldsB1 + p * 8192);
            async_copy16(gB2, ldsB2 + p * 8192);
            async_copy16(gB3, ldsB3 + p * 8192);
            gA0 += 32; gA1 += 32; gB0 += 32; gB1 += 32; gB2 += 32; gB3 += 32;
        }
        const unsigned short* Ab = As + (it & 1) * 4096;
        const unsigned short* Bb = Bs + (it & 1) * 8192;
        frag_ab af[4], bfr[8];
#pragma unroll
        for (int i = 0; i < 4; i++)
            af[i] = *(const frag_ab*)&Ab[(wm + i * 16 + lrow) * 32 + quad * 8];
#pragma unroll
        for (int j = 0; j < 8; j++)
            bfr[j] = *(const frag_ab*)&Bb[(wn + j * 16 + lrow) * 32 + quad * 8];
#pragma unroll
        for (int i = 0; i < 4; i++)
#pragma unroll
            for (int j = 0; j < 8; j++)
                acc[i][j] = __builtin_amdgcn_mfma_f32_16x16x32_bf16(
                    af[i], bfr[j], acc[i][j], 0, 0, 0);
    }

    float bc[8], wc[8];
#pragma unroll
    for (int j = 0; j < 8; j++) {
        const int col = bn + wn + j * 16 + lrow;
        bc[j] = bias[col];
        wc[j] = w3[col];
    }
#pragma unroll
    for (int i = 0; i < 4; i++) {
#pragma unroll
        for (int r = 0; r < 4; r++) {
            float s = 0.0f;
#pragma unroll
            for (int j = 0; j < 8; j++) {
                float v = acc[i][j][r] + bc[j];
                v = v > 0.0f ? v : 0.0f;
                s += v * wc[j];
            }
#pragma unroll
            for (int m = 1; m < 16; m <<= 1) s += __shfl_xor(s, m, 64);
            if (lrow == 0)
                atomicAdd(&op[bm + wm + i * 16 + quad * 4 + r], s);
        }
    }
}

extern "C" void kernel_launch(void* const* d_in, const int* in_sizes, int n_in,
                              void* d_out, int out_size, void* d_ws, size_t ws_size,
                              hipStream_t stream) {
    const float* states  = (const float*)d_in[0];
    const float* actions = (const float*)d_in[1];
    const float* Qw1 = (const float*)d_in[2];
    const float* Qb1 = (const float*)d_in[3];
    const float* Qw2 = (const float*)d_in[4];
    const float* Qb2 = (const float*)d_in[5];
    const float* Qw3 = (const float*)d_in[6];
    const float* Qb3 = (const float*)d_in[7];
    const float* Vw1 = (const float*)d_in[8];
    const float* Vb1 = (const float*)d_in[9];
    const float* Vw2 = (const float*)d_in[10];
    const float* Vb2 = (const float*)d_in[11];
    const float* Vw3 = (const float*)d_in[12];
    const float* Vb3 = (const float*)d_in[13];
    float* out = (float*)d_out;

    // workspace layout (bytes)
    char* ws = (char*)d_ws;
    unsigned short* X    = (unsigned short*)ws;                        // 64 MB
    unsigned short* h1Q  = (unsigned short*)(ws + 67108864);           // 32 MB
    unsigned short* h1V  = (unsigned short*)(ws + 100663296);          // 32 MB
    unsigned short* Qw1t = (unsigned short*)(ws + 134217728);          // 1 MB
    unsigned short* Qw2t = Qw1t + 512 * 1024;
    unsigned short* Vw1t = Qw2t + 512 * 512;
    unsigned short* Vw2t = Vw1t + 512 * 512;

    prep<<<dim3(4672), dim3(256), 0, stream>>>(states, actions, Qw1, Qw2, Vw1, Vw2,
                                               Qb3, Vb3, X, Qw1t, Qw2t, Vw1t, Vw2t, out);

    layer1<<<dim3(1024), dim3(256), 0, stream>>>(X, Qw1t, Vw1t, Qb1, Vb1, h1Q, h1V);
    layer2<<<dim3(1024), dim3(256), 0, stream>>>(h1Q, h1V, Qw2t, Vw2t, Qb2, Vb2, Qw3, Vw3, out);
}